// Round 1
// 242.477 us; speedup vs baseline: 1.0159x; 1.0159x over previous
//
#include <hip/hip_runtime.h>
#include <math.h>
#include <stdint.h>

typedef unsigned short u16;
typedef __attribute__((ext_vector_type(8))) short short8;
typedef __attribute__((ext_vector_type(4))) float f32x4;

// gate scale: 0.125 (attn scale) * log2(e)  -> p = exp2(s * gate)
#define GATE_SCALE 0.18033688011112042f

#if __has_builtin(__builtin_amdgcn_exp2f)
#define FEXP2(x) __builtin_amdgcn_exp2f(x)
#else
#define FEXP2(x) exp2f(x)
#endif

// fp32 -> bf16 round-to-nearest-even
__device__ __forceinline__ u16 f2b(float f) {
    union { float f; unsigned u; } v; v.f = f;
    unsigned r = v.u + 0x7fffu + ((v.u >> 16) & 1u);
    return (u16)(r >> 16);
}
// fp32 -> bf16 round-half-up
__device__ __forceinline__ u16 f2b_hu(float f) {
    union { float f; unsigned u; } v; v.f = f;
    return (u16)((v.u + 0x8000u) >> 16);
}
__device__ __forceinline__ float b2f(u16 u) {
    union { float f; unsigned u; } v; v.u = ((unsigned)u) << 16; return v.f;
}

// async global->LDS, 16B per lane. lds base wave-uniform; HW adds lane*16.
#define GLL16(gsrc, ldsbase) __builtin_amdgcn_global_load_lds(                    \
    (__attribute__((address_space(1))) void*)(uintptr_t)(gsrc),                   \
    (__attribute__((address_space(3))) void*)(uint32_t)(uintptr_t)(ldsbase),      \
    16, 0, 0)

// ---------------------------------------------------------------------------
// K0a: convert x / w_qkv / w_proj to bf16.
// ---------------------------------------------------------------------------
#define NX4  1572864   // 6291456/4
#define NW14 442368
#define NW24 147456
#define NXW4 (NX4 + NW14 + NW24)   // 2162688

__global__ __launch_bounds__(256) void prep_xw(
    const float4* __restrict__ x, const float4* __restrict__ wq,
    const float4* __restrict__ wp,
    ushort4* __restrict__ xb, ushort4* __restrict__ wqb,
    ushort4* __restrict__ wpb)
{
    size_t i = (size_t)blockIdx.x * 256 + threadIdx.x;
    float4 v; ushort4* dst; size_t j;
    if (i < NX4)            { j = i;               v = x[j];  dst = xb;  }
    else if (i < NX4 + NW14){ j = i - NX4;         v = wq[j]; dst = wqb; }
    else                    { j = i - (NX4 + NW14);v = wp[j]; dst = wpb; }
    ushort4 o; o.x = f2b(v.x); o.y = f2b(v.y); o.z = f2b(v.z); o.w = f2b(v.w);
    dst[j] = o;
}

// ---------------------------------------------------------------------------
// K0b: gate = bf16(GATE_SCALE * sigmoid(mask)), permuted into 16x16 MFMA
// C-fragment order (same layout as R3/R4): tile (h,qt,kt); lane (w,l) slot
// (w*64+l)*16, inner idx=i*4+nt <-> row 16w+4fq+i, col nt*16+fr.
// ---------------------------------------------------------------------------
__global__ __launch_bounds__(256) void prep_gate(
    const float4* __restrict__ mask4, u16* __restrict__ gp)
{
    __shared__ u16 L[64][72];                   // +8 u16 pad
    const int bid = blockIdx.x;                 // h*256 + qt*16 + kt
    const int kt = bid & 15, qt = (bid >> 4) & 15, h = bid >> 8;
    const int t = threadIdx.x;

    #pragma unroll
    for (int s = 0; s < 4; ++s) {
        const int idx = t + s * 256;            // 0..1023
        const int row = idx >> 4, c4 = idx & 15;
        float4 v = mask4[(size_t)(h * 1024 + qt * 64 + row) * 256 + kt * 16 + c4];
        L[row][c4 * 4 + 0] = f2b(GATE_SCALE / (1.f + __expf(-v.x)));
        L[row][c4 * 4 + 1] = f2b(GATE_SCALE / (1.f + __expf(-v.y)));
        L[row][c4 * 4 + 2] = f2b(GATE_SCALE / (1.f + __expf(-v.z)));
        L[row][c4 * 4 + 3] = f2b(GATE_SCALE / (1.f + __expf(-v.w)));
    }
    __syncthreads();

    const int w = t >> 6, l = t & 63;
    const int fq = l >> 4, fr = l & 15;
    union { u16 u[16]; float4 f[2]; } vals;
    #pragma unroll
    for (int i = 0; i < 4; ++i)
        #pragma unroll
        for (int nt = 0; nt < 4; ++nt)
            vals.u[i * 4 + nt] = L[16 * w + 4 * fq + i][nt * 16 + fr];
    float4* dst = (float4*)(gp + (size_t)bid * 4096 + (size_t)t * 16);
    dst[0] = vals.f[0];
    dst[1] = vals.f[1];
}

// ---------------------------------------------------------------------------
// K1: QKV GEMM, bf16 MFMA 16x16x32, 128x128 tile, BK=32.
// R5 changes vs R4:
//  * depth-3 staging pipeline (3 LDS buffers, 48 KB) with counted
//    s_waitcnt vmcnt(4) + raw s_barrier -- loads stay in flight across the
//    barrier (AITER/T4 pattern), no vmcnt(0) drain in the main loop.
//  * conflict-free LDS fragment swizzle: seg = fq ^ ((fr>>1)&3) makes each
//    consecutive-8-lane group of a ds_read_b128 cover all 8 16B slots of a
//    128B bank stripe (old fr&3 variant left 2-way collisions -> 4 extra
//    cycles per read, SQ_LDS_BANK_CONFLICT 3.5M/dispatch).
//  * XCD-chunked block swizzle (1152 blocks = 144/XCD) for L2 panel reuse.
// q/k written (B,H,N,64); V written TRANSPOSED (B,H,64,N).
// ---------------------------------------------------------------------------
__global__ __launch_bounds__(256) void qkv_gemm(
    const u16* __restrict__ xb, const u16* __restrict__ wb,
    u16* __restrict__ qb, u16* __restrict__ kb, u16* __restrict__ vb)
{
    __shared__ u16 As[3][4096];
    __shared__ u16 Bs[3][4096];
    const int t = threadIdx.x, l = t & 63, w = t >> 6;
    const int wm = (w & 1) * 64, wn = (w >> 1) * 64;

    // XCD-aware bijective remap: hw linear id -> chunk of 144 per XCD
    const int orig = blockIdx.x + 18 * blockIdx.y;   // gridDim = (18, 64)
    const int nid = (orig & 7) * 144 + (orig >> 3);
    const int m0 = (nid / 18) * 128, c0 = (nid % 18) * 128;

    f32x4 acc[4][4];
    #pragma unroll
    for (int i = 0; i < 4; ++i)
        #pragma unroll
        for (int j = 0; j < 4; ++j) { f32x4 z = {0.f,0.f,0.f,0.f}; acc[i][j] = z; }

    const int srow = l >> 2, sseg = l & 3;
    const int gcol = ((sseg ^ ((srow >> 1) & 3)) << 3);
    const u16* a0 = xb + (size_t)(m0 + w * 16 + srow) * 768 + gcol;
    const u16* a1 = a0 + (size_t)64 * 768;
    const u16* b0p = wb + (size_t)(c0 + w * 16 + srow) * 768 + gcol;
    const u16* b1p = b0p + (size_t)64 * 768;
    const int wofs = w * 512;

    const int fr = l & 15, fq = l >> 4;
    const int fseg = (fq ^ ((fr >> 1) & 3)) << 3;

    auto stage = [&](int bi, int koff) {
        GLL16(a0 + koff, &As[bi][wofs]);
        GLL16(a1 + koff, &As[bi][2048 + wofs]);
        GLL16(b0p + koff, &Bs[bi][wofs]);
        GLL16(b1p + koff, &Bs[bi][2048 + wofs]);
    };

    stage(0, 0);        // kt=0
    stage(1, 32);       // kt=1

    int cur = 0;
    for (int kt = 0; kt < 24; ++kt) {
        // wait for buf[cur]'s 4 loads; keep the next tile's 4 in flight
        if (kt < 23) asm volatile("s_waitcnt vmcnt(4)" ::: "memory");
        else         asm volatile("s_waitcnt vmcnt(0)" ::: "memory");
        __builtin_amdgcn_s_barrier();
        if (kt < 22) {
            const int nn = (cur == 0) ? 2 : cur - 1;   // (cur+2)%3
            stage(nn, (kt + 2) * 32);
        }
        const u16* A = As[cur];
        const u16* B = Bs[cur];
        short8 af[4], bf[4];
        #pragma unroll
        for (int mt = 0; mt < 4; ++mt)
            af[mt] = *(const short8*)&A[(wm + mt * 16 + fr) * 32 + fseg];
        #pragma unroll
        for (int nt = 0; nt < 4; ++nt)
            bf[nt] = *(const short8*)&B[(wn + nt * 16 + fr) * 32 + fseg];
        #pragma unroll
        for (int mt = 0; mt < 4; ++mt)
            #pragma unroll
            for (int nt = 0; nt < 4; ++nt)
                acc[mt][nt] = __builtin_amdgcn_mfma_f32_16x16x32_bf16(
                    af[mt], bf[nt], acc[mt][nt], 0, 0, 0);
        cur = (cur == 2) ? 0 : cur + 1;
    }

    const int b = m0 >> 10;
    const int n0 = m0 & 1023;
    #pragma unroll
    for (int nt = 0; nt < 4; ++nt) {
        const int c = c0 + wn + nt * 16 + fr;
        const int which = c / 768;
        const int rem = c - which * 768;
        const int h = rem >> 6, d = rem & 63;
        if (which < 2) {
            u16* dst = ((which == 0) ? qb : kb)
                       + ((size_t)(b * 12 + h) * 1024) * 64 + d;
            #pragma unroll
            for (int mt = 0; mt < 4; ++mt)
                #pragma unroll
                for (int r = 0; r < 4; ++r) {
                    const int n = n0 + wm + mt * 16 + fq * 4 + r;
                    dst[(size_t)n * 64] = f2b(acc[mt][nt][r]);
                }
        } else {
            u16* dst = vb + ((size_t)(b * 12 + h) * 64 + d) * 1024
                          + n0 + wm + fq * 4;
            #pragma unroll
            for (int mt = 0; mt < 4; ++mt) {
                ushort4 pk;
                pk.x = f2b(acc[mt][nt][0]); pk.y = f2b(acc[mt][nt][1]);
                pk.z = f2b(acc[mt][nt][2]); pk.w = f2b(acc[mt][nt][3]);
                *(ushort4*)(dst + mt * 16) = pk;
            }
        }
    }
}

// ---------------------------------------------------------------------------
// K2: flash attention, 16x16x32 MFMA (R4-verified fragments/swizzles/gate
// prefetch), TWO 64-row Q-tiles per block. Unchanged from R4.
// ---------------------------------------------------------------------------
__global__ __launch_bounds__(256, 3) void flash_attn(
    const u16* __restrict__ qb, const u16* __restrict__ kb,
    const u16* __restrict__ vt, const u16* __restrict__ gperm,
    u16* __restrict__ aob)
{
    __shared__ u16 Qs[8192], Ks[4096], Vts[4096], Ps[4096];
    const int t = threadIdx.x, l = t & 63, w = t >> 6;
    const int bid = blockIdx.x;                 // bh*8 + qtb
    const int qtb = bid & 7, bh = bid >> 3;
    const int h = bh % 12, b = bh / 12;
    const int q0 = qtb * 128;

    const u16* hq = qb + (size_t)bh * 65536;
    const u16* hk = kb + (size_t)bh * 65536;
    const u16* hv = vt + (size_t)bh * 65536;
    const u16* hgb = gperm + ((size_t)h * 256 + qtb * 32) * 4096 + (w * 64 + l) * 16;

    const int sr = l >> 3, ss = l & 7;
    const int sg = ((ss ^ (sr & 7)) << 3);
    const int j0 = w * 2, j1 = j0 + 1;

    #pragma unroll
    for (int jq = 0; jq < 4; ++jq) {
        const int j = w * 4 + jq;
        GLL16(hq + (size_t)(q0 + j * 8 + sr) * 64 + sg, Qs + j * 512);
    }
    GLL16(hk + (size_t)(j0 * 8 + sr) * 64 + sg, Ks + j0 * 512);
    GLL16(hk + (size_t)(j1 * 8 + sr) * 64 + sg, Ks + j1 * 512);
    GLL16(hv + (size_t)(j0 * 8 + sr) * 1024 + sg, Vts + j0 * 512);
    GLL16(hv + (size_t)(j1 * 8 + sr) * 1024 + sg, Vts + j1 * 512);
    __syncthreads();

    const int fq = l >> 4, fr = l & 15;
    const int sega = ((fq ^ (fr & 7)) << 3);
    const int segb = (((4 + fq) ^ (fr & 7)) << 3);

    short8 aq[2][2];
    #pragma unroll
    for (int qh = 0; qh < 2; ++qh) {
        const int row = 16 * w + fr;
        aq[qh][0] = *(const short8*)&Qs[qh * 4096 + row * 64 + sega];
        aq[qh][1] = *(const short8*)&Qs[qh * 4096 + row * 64 + segb];
    }

    short8 gn[4];
    gn[0] = *(const short8*)(hgb);
    gn[1] = *(const short8*)(hgb + 8);
    gn[2] = *(const short8*)(hgb + 65536);
    gn[3] = *(const short8*)(hgb + 65536 + 8);

    float l_part[2][4] = {{0.f,0.f,0.f,0.f},{0.f,0.f,0.f,0.f}};
    f32x4 o[2][4];
    #pragma unroll
    for (int qh = 0; qh < 2; ++qh)
        #pragma unroll
        for (int nt = 0; nt < 4; ++nt) { f32x4 z = {0.f,0.f,0.f,0.f}; o[qh][nt] = z; }

    for (int kt = 0; kt < 16; ++kt) {
        short8 g[4];
        #pragma unroll
        for (int s = 0; s < 4; ++s) g[s] = gn[s];
        if (kt < 15) {
            const size_t go = (size_t)(kt + 1) * 4096;
            gn[0] = *(const short8*)(hgb + go);
            gn[1] = *(const short8*)(hgb + go + 8);
            gn[2] = *(const short8*)(hgb + 65536 + go);
            gn[3] = *(const short8*)(hgb + 65536 + go + 8);
        }

        f32x4 sv[2][4];
        #pragma unroll
        for (int nt = 0; nt < 4; ++nt) {
            short8 kf0 = *(const short8*)&Ks[(nt * 16 + fr) * 64 + sega];
            short8 kf1 = *(const short8*)&Ks[(nt * 16 + fr) * 64 + segb];
            f32x4 z0 = {0.f,0.f,0.f,0.f};
            z0 = __builtin_amdgcn_mfma_f32_16x16x32_bf16(aq[0][0], kf0, z0, 0, 0, 0);
            z0 = __builtin_amdgcn_mfma_f32_16x16x32_bf16(aq[0][1], kf1, z0, 0, 0, 0);
            sv[0][nt] = z0;
            f32x4 z1 = {0.f,0.f,0.f,0.f};
            z1 = __builtin_amdgcn_mfma_f32_16x16x32_bf16(aq[1][0], kf0, z1, 0, 0, 0);
            z1 = __builtin_amdgcn_mfma_f32_16x16x32_bf16(aq[1][1], kf1, z1, 0, 0, 0);
            sv[1][nt] = z1;
        }

        short8 ap[2][2];
        #pragma unroll
        for (int qh = 0; qh < 2; ++qh) {
            #pragma unroll
            for (int i = 0; i < 4; ++i) {
                const int pr = 4 * fq + i;
                #pragma unroll
                for (int nt = 0; nt < 4; ++nt) {
                    const int idx = i * 4 + nt;
                    const float gv = b2f((u16)(idx < 8 ? g[2 * qh][idx]
                                                       : g[2 * qh + 1][idx - 8]));
                    const float p = FEXP2(sv[qh][nt][i] * gv);
                    l_part[qh][i] += p;
                    const int col = nt * 16 + fr;
                    Ps[w * 1024 + pr * 64 + (((col >> 3) ^ (pr & 7)) << 3) + (col & 7)]
                        = f2b_hu(p);
                }
            }
            ap[qh][0] = *(const short8*)&Ps[w * 1024 + fr * 64 + sega];
            ap[qh][1] = *(const short8*)&Ps[w * 1024 + fr * 64 + segb];
        }

        #pragma unroll
        for (int nt = 0; nt < 4; ++nt) {
            short8 vf0 = *(const short8*)&Vts[(nt * 16 + fr) * 64 + sega];
            short8 vf1 = *(const short8*)&Vts[(nt * 16 + fr) * 64 + segb];
            o[0][nt] = __builtin_amdgcn_mfma_f32_16x16x32_bf16(ap[0][0], vf0, o[0][nt], 0, 0, 0);
            o[0][nt] = __builtin_amdgcn_mfma_f32_16x16x32_bf16(ap[0][1], vf1, o[0][nt], 0, 0, 0);
            o[1][nt] = __builtin_amdgcn_mfma_f32_16x16x32_bf16(ap[1][0], vf0, o[1][nt], 0, 0, 0);
            o[1][nt] = __builtin_amdgcn_mfma_f32_16x16x32_bf16(ap[1][1], vf1, o[1][nt], 0, 0, 0);
        }

        if (kt < 15) {
            __syncthreads();
            const size_t ko = (size_t)(kt + 1) * 64;
            GLL16(hk + (ko + j0 * 8 + sr) * 64 + sg, Ks + j0 * 512);
            GLL16(hk + (ko + j1 * 8 + sr) * 64 + sg, Ks + j1 * 512);
            GLL16(hv + (size_t)(j0 * 8 + sr) * 1024 + ko + sg, Vts + j0 * 512);
            GLL16(hv + (size_t)(j1 * 8 + sr) * 1024 + ko + sg, Vts + j1 * 512);
            __syncthreads();
        }
    }

    #pragma unroll
    for (int qh = 0; qh < 2; ++qh) {
        #pragma unroll
        for (int i = 0; i < 4; ++i) {
            float s = l_part[qh][i];
            s += __shfl_xor(s, 1, 16);
            s += __shfl_xor(s, 2, 16);
            s += __shfl_xor(s, 4, 16);
            s += __shfl_xor(s, 8, 16);
            const float inv = 1.f / s;
            const int n = q0 + qh * 64 + 16 * w + 4 * fq + i;
            const size_t rowoff = ((size_t)b * 1024 + n) * 768 + h * 64;
            #pragma unroll
            for (int nt = 0; nt < 4; ++nt)
                aob[rowoff + nt * 16 + fr] = f2b(o[qh][nt][i] * inv);
        }
    }
}

// ---------------------------------------------------------------------------
// K3: output projection, bf16 MFMA, fp32 out + bias.
// Same R5 upgrades as K1: depth-3 counted-vmcnt pipeline, conflict-free
// fragment swizzle, XCD-chunked block swizzle (384 blocks = 48/XCD).
// ---------------------------------------------------------------------------
__global__ __launch_bounds__(256) void proj_gemm(
    const u16* __restrict__ aob, const u16* __restrict__ wb,
    const float* __restrict__ bproj, float* __restrict__ out)
{
    __shared__ u16 As[3][4096];
    __shared__ u16 Bs[3][4096];
    const int t = threadIdx.x, l = t & 63, w = t >> 6;
    const int wm = (w & 1) * 64, wn = (w >> 1) * 64;

    const int orig = blockIdx.x + 6 * blockIdx.y;    // gridDim = (6, 64)
    const int nid = (orig & 7) * 48 + (orig >> 3);
    const int m0 = (nid / 6) * 128, c0 = (nid % 6) * 128;

    f32x4 acc[4][4];
    #pragma unroll
    for (int i = 0; i < 4; ++i)
        #pragma unroll
        for (int j = 0; j < 4; ++j) { f32x4 z = {0.f,0.f,0.f,0.f}; acc[i][j] = z; }

    const int srow = l >> 2, sseg = l & 3;
    const int gcol = ((sseg ^ ((srow >> 1) & 3)) << 3);
    const u16* a0 = aob + (size_t)(m0 + w * 16 + srow) * 768 + gcol;
    const u16* a1 = a0 + (size_t)64 * 768;
    const u16* b0p = wb + (size_t)(c0 + w * 16 + srow) * 768 + gcol;
    const u16* b1p = b0p + (size_t)64 * 768;
    const int wofs = w * 512;

    const int fr = l & 15, fq = l >> 4;
    const int fseg = (fq ^ ((fr >> 1) & 3)) << 3;

    auto stage = [&](int bi, int koff) {
        GLL16(a0 + koff, &As[bi][wofs]);
        GLL16(a1 + koff, &As[bi][2048 + wofs]);
        GLL16(b0p + koff, &Bs[bi][wofs]);
        GLL16(b1p + koff, &Bs[bi][2048 + wofs]);
    };

    stage(0, 0);
    stage(1, 32);

    int cur = 0;
    for (int kt = 0; kt < 24; ++kt) {
        if (kt < 23) asm volatile("s_waitcnt vmcnt(4)" ::: "memory");
        else         asm volatile("s_waitcnt vmcnt(0)" ::: "memory");
        __builtin_amdgcn_s_barrier();
        if (kt < 22) {
            const int nn = (cur == 0) ? 2 : cur - 1;
            stage(nn, (kt + 2) * 32);
        }
        const u16* A = As[cur];
        const u16* B = Bs[cur];
        short8 af[4], bf[4];
        #pragma unroll
        for (int mt = 0; mt < 4; ++mt)
            af[mt] = *(const short8*)&A[(wm + mt * 16 + fr) * 32 + fseg];
        #pragma unroll
        for (int nt = 0; nt < 4; ++nt)
            bf[nt] = *(const short8*)&B[(wn + nt * 16 + fr) * 32 + fseg];
        #pragma unroll
        for (int mt = 0; mt < 4; ++mt)
            #pragma unroll
            for (int nt = 0; nt < 4; ++nt)
                acc[mt][nt] = __builtin_amdgcn_mfma_f32_16x16x32_bf16(
                    af[mt], bf[nt], acc[mt][nt], 0, 0, 0);
        cur = (cur == 2) ? 0 : cur + 1;
    }

    #pragma unroll
    for (int nt = 0; nt < 4; ++nt) {
        const int c = c0 + wn + nt * 16 + fr;
        const float bias = bproj[c];
        #pragma unroll
        for (int mt = 0; mt < 4; ++mt)
            #pragma unroll
            for (int r = 0; r < 4; ++r) {
                const int m = m0 + wm + mt * 16 + fq * 4 + r;
                out[(size_t)m * 768 + c] = acc[mt][nt][r] + bias;
            }
    }
}

// ---------------------------------------------------------------------------
extern "C" void kernel_launch(void* const* d_in, const int* in_sizes, int n_in,
                              void* d_out, int out_size, void* d_ws, size_t ws_size,
                              hipStream_t stream)
{
    const float* x     = (const float*)d_in[0];
    const float* wqkv  = (const float*)d_in[1];
    const float* wproj = (const float*)d_in[2];
    const float* bproj = (const float*)d_in[3];
    const float* mask  = (const float*)d_in[4];
    float* out = (float*)d_out;

    char* ws = (char*)d_ws;
    u16* gperm  = (u16*)(ws);               // 25,165,824 B
    u16* xb     = (u16*)(ws + 25165824);    // 12,582,912 B
    u16* wqkvb  = (u16*)(ws + 37748736);    //  3,538,944 B
    u16* wprojb = (u16*)(ws + 41287680);    //  1,179,648 B
    u16* qb     = (u16*)(ws + 42467328);    // 12,582,912 B
    u16* kb     = (u16*)(ws + 55050240);    // 12,582,912 B
    u16* vb     = (u16*)(ws + 67633152);    // 12,582,912 B (transposed: B,H,64,N)
    u16* aob    = (u16*)(ws + 80216064);    // 12,582,912 B  (total 92.8 MB)

    prep_xw<<<NXW4 / 256, 256, 0, stream>>>(
        (const float4*)x, (const float4*)wqkv, (const float4*)wproj,
        (ushort4*)xb, (ushort4*)wqkvb, (ushort4*)wprojb);

    prep_gate<<<3072, 256, 0, stream>>>((const float4*)mask, gperm);

    qkv_gemm<<<dim3(18, 64), 256, 0, stream>>>(xb, wqkvb, qb, kb, vb);

    flash_attn<<<768, 256, 0, stream>>>(qb, kb, vb, gperm, aob);

    proj_gemm<<<dim3(6, 64), 256, 0, stream>>>(aob, wprojb, bproj, out);
}